// Round 8
// baseline (365.289 us; speedup 1.0000x reference)
//
#include <hip/hip_runtime.h>

typedef unsigned int u32;
typedef unsigned short u16;
using s16x8 = __attribute__((ext_vector_type(8))) short;   // 8 bf16 (4 VGPRs)
using f32x4 = __attribute__((ext_vector_type(4))) float;

static constexpr int NB = 512;     // batch
static constexpr int L  = 512;     // points per cloud
static constexpr int F  = 64;      // input features
static constexpr int H  = 128;     // hidden features
static constexpr float EPS = 1e-5f;
static const size_t NTOT = (size_t)NB * L * 2 * H;   // g tail offset in out

// round-to-nearest-even fp32 -> bf16 bits
__device__ __forceinline__ u32 bf_rne(float f) {
    u32 u = __float_as_uint(f);
    return (u + 0x7fffu + ((u >> 16) & 1u)) >> 16;
}

// ---------------------------------------------------------------------------
// K1: round-7 structure scaled to 512-thread blocks (8 waves, 128 rows each,
// grid = NB*4 = 2048):
//  - thread-cap occupancy: 4 blocks/CU x 512 thr = 2048 = 32 waves (100%),
//    vs round-7's 20 waves. LDS stays 32768 B (not binding: 4x32K=128K).
//    __launch_bounds__(512,8) pins VGPR <= 64 (R1's fused 512-thr kernel
//    with this same core compiled at exactly 64).
//  - W-convert total work drops 4x (2048 blocks x 2 staging iters vs
//    4096 x 4); atomicMax count halves.
//  - transpose: two 64-row passes through the same 32 KB XOR-swizzled
//    [64][128] buffer (waves 0-3 fill pass 0, waves 4-7 pass 1; whole
//    block stores each pass). Same conflict-free write/read patterns as
//    round 7, one extra barrier.
//  - SIGNED-int atomicMax into the g tail (poison 0xAA.. negative as int,
//    y >= 0) -> no zeroing pass (verified rounds 5-7).
// ---------------------------------------------------------------------------
__global__ __launch_bounds__(512, 8)
void k1_gemm_ln(const float* __restrict__ xp, const int* __restrict__ maskp,
                const float* __restrict__ Wp, const float* __restrict__ bp,
                const float* __restrict__ gp, const float* __restrict__ betap,
                float* __restrict__ outp)
{
    __shared__ __align__(16) char smem[32768];
    u16*   whi = (u16*)smem;                 // [0,16K): B-frag-ordered W hi
    u16*   wlo = (u16*)(smem + 16384);       // [16K,32K): B-frag-ordered W lo
    float* tb  = (float*)smem;               // [64][128] f32, XOR-swizzled
    float* gsh = (float*)smem;               // [8][128] aliases tb after use

    const int bx  = blockIdx.x;
    const int n   = bx >> 2;
    const int c2  = bx & 3;                  // 128-row chunk within cloud
    const int tid = threadIdx.x;             // 0..511
    const int w   = tid >> 6;                // wave 0..7
    const int lane = tid & 63;
    const int m   = lane & 15;
    const int q   = lane >> 4;

    // ---- stage W as bf16 hi/lo fragments. Group g (0..1023) = frag (t,s) x lane:
    //      t=g>>7, s=(g>>6)&1, ln=g&63; element j: W[t*16+(ln&15)][s*32+(ln>>4)*8+j]
    #pragma unroll
    for (int it = 0; it < 2; ++it) {
        const int g  = it * 512 + tid;
        const int t  = g >> 7;
        const int s  = (g >> 6) & 1;
        const int ln = g & 63;
        const int mm = ln & 15;
        const int qq = ln >> 4;
        const float* src = Wp + (t * 16 + mm) * F + s * 32 + qq * 8;
        const float4 a = *(const float4*)src;
        const float4 b = *(const float4*)(src + 4);
        const float xv[8] = {a.x, a.y, a.z, a.w, b.x, b.y, b.z, b.w};
        u32 hi[8], lo[8];
        #pragma unroll
        for (int j = 0; j < 8; ++j) {
            hi[j] = bf_rne(xv[j]);
            const float hf = __uint_as_float(hi[j] << 16);
            lo[j] = bf_rne(xv[j] - hf);
        }
        uint4 ph, pl;
        ph.x = hi[0] | (hi[1] << 16); ph.y = hi[2] | (hi[3] << 16);
        ph.z = hi[4] | (hi[5] << 16); ph.w = hi[6] | (hi[7] << 16);
        pl.x = lo[0] | (lo[1] << 16); pl.y = lo[2] | (lo[3] << 16);
        pl.z = lo[4] | (lo[5] << 16); pl.w = lo[6] | (lo[7] << 16);
        *(uint4*)&whi[g * 8] = ph;
        *(uint4*)&wlo[g * 8] = pl;
    }

    // ---- A fragments: x rows rb..rb+15, split hi/lo (global -> regs, no LDS)
    const int rb = n * L + c2 * 128 + w * 16;
    int mk[4];
    #pragma unroll
    for (int r = 0; r < 4; ++r) mk[r] = maskp[rb + q * 4 + r];

    s16x8 Ahi[2], Alo[2];
    #pragma unroll
    for (int s = 0; s < 2; ++s) {
        const float* xs = xp + (size_t)(rb + m) * F + s * 32 + q * 8;
        const float4 a = *(const float4*)xs;
        const float4 b = *(const float4*)(xs + 4);
        const float xv[8] = {a.x, a.y, a.z, a.w, b.x, b.y, b.z, b.w};
        #pragma unroll
        for (int j = 0; j < 8; ++j) {
            const u32 hb = bf_rne(xv[j]);
            const float hf = __uint_as_float(hb << 16);
            Ahi[s][j] = (short)hb;
            Alo[s][j] = (short)bf_rne(xv[j] - hf);
        }
    }
    __syncthreads();

    // ---- MFMA: 8 h-tiles x 2 k-steps x 3 split terms
    f32x4 acc[8] = {};
    #pragma unroll
    for (int t = 0; t < 8; ++t) {
        #pragma unroll
        for (int s = 0; s < 2; ++s) {
            const s16x8 Bh = *(const s16x8*)&whi[((t * 2 + s) * 64 + lane) * 8];
            const s16x8 Bl = *(const s16x8*)&wlo[((t * 2 + s) * 64 + lane) * 8];
            acc[t] = __builtin_amdgcn_mfma_f32_16x16x32_bf16(Ahi[s], Bh, acc[t], 0, 0, 0);
            acc[t] = __builtin_amdgcn_mfma_f32_16x16x32_bf16(Alo[s], Bh, acc[t], 0, 0, 0);
            acc[t] = __builtin_amdgcn_mfma_f32_16x16x32_bf16(Ahi[s], Bl, acc[t], 0, 0, 0);
        }
    }

    // ---- per-column params (h = t*16 + m); L2/L1-hot scalar loads
    float bias[8], gam[8], bet[8];
    #pragma unroll
    for (int t = 0; t < 8; ++t) {
        const int h = t * 16 + m;
        bias[t] = bp[h];
        gam[t]  = gp[h];
        bet[t]  = betap[h];
    }
    #pragma unroll
    for (int t = 0; t < 8; ++t)
        #pragma unroll
        for (int r = 0; r < 4; ++r)
            acc[t][r] += bias[t];

    // ---- LayerNorm stats. C/D layout: col=lane&15, row=q*4+reg.
    float sum[4] = {0, 0, 0, 0}, sq[4] = {0, 0, 0, 0};
    #pragma unroll
    for (int t = 0; t < 8; ++t)
        #pragma unroll
        for (int r = 0; r < 4; ++r) {
            const float v = acc[t][r];
            sum[r] += v; sq[r] += v * v;
        }
    #pragma unroll
    for (int r = 0; r < 4; ++r) {
        #pragma unroll
        for (int o = 1; o < 16; o <<= 1) {
            sum[r] += __shfl_xor(sum[r], o);
            sq[r]  += __shfl_xor(sq[r],  o);
        }
    }
    float mu[4], rs[4];
    #pragma unroll
    for (int r = 0; r < 4; ++r) {
        mu[r] = sum[r] * (1.0f / 128.0f);
        const float var = sq[r] * (1.0f / 128.0f) - mu[r] * mu[r];
        rs[r] = rsqrtf(var + EPS);
    }

    // ---- normalize, relu -> y in regs; masked max in regs
    float gmax[8];
    #pragma unroll
    for (int t = 0; t < 8; ++t) {
        float gm = 0.0f;
        #pragma unroll
        for (int r = 0; r < 4; ++r) {
            float y = (acc[t][r] - mu[r]) * rs[r] * gam[t] + bet[t];
            y = fmaxf(y, 0.0f);
            acc[t][r] = y;
            if (mk[r] != 0) gm = fmaxf(gm, y);
        }
        gm = fmaxf(gm, __shfl_xor(gm, 16));
        gm = fmaxf(gm, __shfl_xor(gm, 32));
        gmax[t] = gm;          // butterfly: valid on all lanes
    }

    // ---- transpose + store, two 64-row passes through the 32 KB buffer
    const size_t growbase = (size_t)n * L + c2 * 128;
    #pragma unroll
    for (int p = 0; p < 2; ++p) {
        // p=0: barrier protects whi/wlo (B-frag ds_reads drained);
        // p=1: barrier protects pass-0's tb reads
        __syncthreads();
        if ((w >> 2) == p) {
            const int lr = (w & 3) * 16 + q * 4;   // local row base 0..60
            #pragma unroll
            for (int t = 0; t < 8; ++t)
                #pragma unroll
                for (int r = 0; r < 4; ++r) {
                    const int row = lr + r;
                    tb[row * 128 + ((t * 16 + m) ^ ((row & 7) << 2))] = acc[t][r];
                }
        }
        __syncthreads();
        // whole block stores 64 rows x 512B first-halves, fully coalesced
        {
            const int c   = tid & 31;          // float4 index within row-half
            const int rr0 = tid >> 5;          // 0..15
            #pragma unroll
            for (int i = 0; i < 4; ++i) {
                const int rr = i * 16 + rr0;
                const float4 v = *(const float4*)&tb[rr * 128 + ((c * 4) ^ ((rr & 7) << 2))];
                *(float4*)(outp + (growbase + p * 64 + rr) * (2 * H) + c * 4) = v;
            }
        }
    }

    // ---- block masked-max: gsh (4 KB) aliases tb behind a barrier
    __syncthreads();
    if (q == 0) {
        #pragma unroll
        for (int t = 0; t < 8; ++t)
            gsh[w * H + t * 16 + m] = gmax[t];
    }
    __syncthreads();
    if (tid < H) {
        float mx = gsh[tid];
        #pragma unroll
        for (int ww = 1; ww < 8; ++ww) mx = fmaxf(mx, gsh[ww * H + tid]);
        atomicMax((int*)(outp + NTOT + (size_t)n * H + tid),
                  (int)__float_as_uint(mx));
    }
}

// ---------------------------------------------------------------------------
// K2: one block per (n, 64-row chunk): read final g from the out tail
// (L2-hot, 512 B per cloud) and broadcast into the second half of rows.
// ---------------------------------------------------------------------------
__global__ __launch_bounds__(256)
void k2_bcast(float* __restrict__ outp)
{
    const int bx  = blockIdx.x;
    const int n   = bx >> 3;
    const int c2  = bx & 7;
    const int tid = threadIdx.x;
    const int tc  = tid & 31;
    const int tr  = tid >> 5;
    const int h0  = tc * 4;

    const float4 g4 = *(const float4*)(outp + NTOT + (size_t)n * H + h0);

    #pragma unroll
    for (int ri = 0; ri < 8; ++ri) {
        const int l = c2 * 64 + tr * 8 + ri;
        *(float4*)(outp + ((size_t)n * L + l) * (2 * H) + H + h0) = g4;
    }
}

extern "C" void kernel_launch(void* const* d_in, const int* in_sizes, int n_in,
                              void* d_out, int out_size, void* d_ws, size_t ws_size,
                              hipStream_t stream)
{
    (void)in_sizes; (void)n_in; (void)out_size; (void)d_ws; (void)ws_size;
    const float* x     = (const float*)d_in[0];
    const int*   mask  = (const int*)d_in[1];
    const float* W     = (const float*)d_in[2];
    const float* b     = (const float*)d_in[3];
    const float* gamma = (const float*)d_in[4];
    const float* beta  = (const float*)d_in[5];
    float* out = (float*)d_out;

    k1_gemm_ln<<<dim3(NB * 4), dim3(512), 0, stream>>>(
        x, mask, W, b, gamma, beta, out);
    k2_bcast<<<dim3(NB * 8), dim3(256), 0, stream>>>(out);
}